// Round 2
// baseline (832.964 us; speedup 1.0000x reference)
//
#include <hip/hip_runtime.h>
#include <math.h>

// Problem constants
#define NTOK 16384     // B*N_PATCH = 64*256
#define NPRO 1005      // C*K = 201*5
#define DIMD 768
#define CKD  1005
#define CC   201
#define KKp  5
#define BGC  200       // background class id (C-1)

// d_out section offsets (floats)
#define OUT_LOGITS   0
#define OUT_IMG      16465920
#define OUT_CLS      (OUT_IMG + 64320)
#define OUT_PART     (OUT_CLS + 12800)
#define OUT_NEWPROTO (OUT_PART + 16384)
#define OUT_PSEUDO   (OUT_NEWPROTO + 771840)

// ws byte offsets
#define WOFF_PACC    0
#define WOFF_COUNTS  3087360
#define WOFF_FLAG    3088384
#define WS_ZERO_B    3088640
#define WOFF_INVTOK  3088640
#define WOFF_INVPRO  3154176
#define WOFF_PL      3158272
#define WOFF_Q       3223808
#define WOFF_COLSUM  3551488
#define WOFF_OFFSETS 3555584
#define WOFF_CURSORS 3557632
#define WOFF_ORDER   3558656

// ---------------- norms: 1/(||row||+eps) for tokens and prototypes ----------
__global__ __launch_bounds__(256) void norms_kernel(const float* __restrict__ tok,
                                                    const float* __restrict__ pro,
                                                    float* __restrict__ inv_tok,
                                                    float* __restrict__ inv_pro) {
  int wid = (blockIdx.x * 256 + threadIdx.x) >> 6;   // one wave per row
  int lane = threadIdx.x & 63;
  if (wid >= NTOK + NPRO) return;
  const float* src = (wid < NTOK) ? tok + (size_t)wid * DIMD
                                  : pro + (size_t)(wid - NTOK) * DIMD;
  const float4* s4 = (const float4*)src;
  float s = 0.0f;
#pragma unroll
  for (int p = 0; p < 3; ++p) {
    float4 v = s4[p * 64 + lane];
    s += v.x * v.x + v.y * v.y + v.z * v.z + v.w * v.w;
  }
#pragma unroll
  for (int off = 32; off; off >>= 1) s += __shfl_xor(s, off, 64);
  if (lane == 0) {
    float inv = 1.0f / (sqrtf(s) + 1e-12f);
    if (wid < NTOK) inv_tok[wid] = inv;
    else            inv_pro[wid - NTOK] = inv;
  }
}

// ---------------- mask dtype probe -------------------------------------------
// Distinguish byte-packed bool / int32 bool / float32 bool device-side.
// Probe only the first 4096 u32 words (16 KiB) — valid in all three layouts.
//   word == 0x3F800000                  -> float32 1.0f          (bit0)
//   word > 1 && word != 0x3F800000      -> byte-packed {0,1}^4   (bit1)
//   (byte-packed words are sums of {0,1} bytes; never 0x3F800000)
// neither bit set -> int32 bools.
__global__ void maskprobe_kernel(const unsigned* __restrict__ masks, int* __restrict__ flag) {
  int i = blockIdx.x * 256 + threadIdx.x;
  if (i < 4096) {
    unsigned v = masks[i];
    if (v == 0x3F800000u)      atomicOr(flag, 1);
    else if (v > 1u)           atomicOr(flag, 2);
  }
}

// ---------------- GEMM: C[16384][1005] = (A*invA) . (B*invB)^T --------------
__global__ __launch_bounds__(256) void gemm_kernel(const float* __restrict__ A,
                                                   const float* __restrict__ Bm,
                                                   const float* __restrict__ invA,
                                                   const float* __restrict__ invB,
                                                   float* __restrict__ C) {
  __shared__ float As[16][128];
  __shared__ float Bs[16][128];
  const int tid = threadIdx.x;
  const int tx = tid & 15, ty = tid >> 4;
  const int m0 = blockIdx.x * 128;
  const int n0 = blockIdx.y * 128;
  const int r  = tid >> 2;          // 0..63
  const int kc = (tid & 3) << 2;    // 0,4,8,12

  const int arow0 = m0 + r, arow1 = arow0 + 64;
  const int bcol0 = n0 + r, bcol1 = bcol0 + 64;
  const float ai0 = invA[arow0], ai1 = invA[arow1];
  const float bi0 = (bcol0 < NPRO) ? invB[bcol0] : 0.0f;
  const float bi1 = (bcol1 < NPRO) ? invB[bcol1] : 0.0f;
  const float* aPtr0 = A + (size_t)arow0 * DIMD + kc;
  const float* aPtr1 = A + (size_t)arow1 * DIMD + kc;
  const float* bPtr0 = Bm + (size_t)((bcol0 < NPRO) ? bcol0 : 0) * DIMD + kc;
  const float* bPtr1 = Bm + (size_t)((bcol1 < NPRO) ? bcol1 : 0) * DIMD + kc;

  float4 aR0 = *(const float4*)aPtr0;
  float4 aR1 = *(const float4*)aPtr1;
  float4 bR0 = *(const float4*)bPtr0;
  float4 bR1 = *(const float4*)bPtr1;

  float acc[8][8];
#pragma unroll
  for (int i = 0; i < 8; ++i)
#pragma unroll
    for (int j = 0; j < 8; ++j) acc[i][j] = 0.0f;

  for (int kt = 0; kt < 48; ++kt) {
    As[kc + 0][r]      = aR0.x * ai0;
    As[kc + 1][r]      = aR0.y * ai0;
    As[kc + 2][r]      = aR0.z * ai0;
    As[kc + 3][r]      = aR0.w * ai0;
    As[kc + 0][r + 64] = aR1.x * ai1;
    As[kc + 1][r + 64] = aR1.y * ai1;
    As[kc + 2][r + 64] = aR1.z * ai1;
    As[kc + 3][r + 64] = aR1.w * ai1;
    Bs[kc + 0][r]      = bR0.x * bi0;
    Bs[kc + 1][r]      = bR0.y * bi0;
    Bs[kc + 2][r]      = bR0.z * bi0;
    Bs[kc + 3][r]      = bR0.w * bi0;
    Bs[kc + 0][r + 64] = bR1.x * bi1;
    Bs[kc + 1][r + 64] = bR1.y * bi1;
    Bs[kc + 2][r + 64] = bR1.z * bi1;
    Bs[kc + 3][r + 64] = bR1.w * bi1;
    __syncthreads();
    if (kt < 47) {
      const int off = (kt + 1) * 16;
      aR0 = *(const float4*)(aPtr0 + off);
      aR1 = *(const float4*)(aPtr1 + off);
      bR0 = *(const float4*)(bPtr0 + off);
      bR1 = *(const float4*)(bPtr1 + off);
    }
#pragma unroll
    for (int k = 0; k < 16; ++k) {
      float4 a0 = *(const float4*)&As[k][ty << 2];
      float4 a1 = *(const float4*)&As[k][64 + (ty << 2)];
      float4 b0 = *(const float4*)&Bs[k][tx << 2];
      float4 b1 = *(const float4*)&Bs[k][64 + (tx << 2)];
      float av[8] = {a0.x, a0.y, a0.z, a0.w, a1.x, a1.y, a1.z, a1.w};
      float bv[8] = {b0.x, b0.y, b0.z, b0.w, b1.x, b1.y, b1.z, b1.w};
#pragma unroll
      for (int i = 0; i < 8; ++i)
#pragma unroll
        for (int j = 0; j < 8; ++j)
          acc[i][j] = fmaf(av[i], bv[j], acc[i][j]);
    }
    __syncthreads();
  }

  const int nvalid = NPRO - n0;   // >=128 except last N-block (109)
#pragma unroll
  for (int i = 0; i < 8; ++i) {
    int row = m0 + ((i < 4) ? (ty * 4 + i) : (64 + ty * 4 + (i - 4)));
    float* crow = C + (size_t)row * CKD + n0;
    int c0 = tx * 4, c1 = 64 + tx * 4;
    if (nvalid >= 128) {
      *(float4*)(crow + c0) = make_float4(acc[i][0], acc[i][1], acc[i][2], acc[i][3]);
      *(float4*)(crow + c1) = make_float4(acc[i][4], acc[i][5], acc[i][6], acc[i][7]);
    } else {
#pragma unroll
      for (int j = 0; j < 4; ++j) {
        if (c0 + j < nvalid) crow[c0 + j] = acc[i][j];
        if (c1 + j < nvalid) crow[c1 + j] = acc[i][4 + j];
      }
    }
  }
}

// ---------------- mean over patches: img[b][ck] --------------------------------
__global__ __launch_bounds__(256) void mean_kernel(const float* __restrict__ L,
                                                   float* __restrict__ img) {
  int gid = blockIdx.x * 256 + threadIdx.x;
  if (gid >= 64 * CKD) return;
  int b = gid / CKD, ck = gid - b * CKD;
  const float* p = L + (size_t)b * 256 * CKD + ck;
  float s = 0.0f;
  for (int n = 0; n < 256; ++n) s += p[(size_t)n * CKD];
  img[gid] = s * (1.0f / 256.0f);
}

// ---------------- class logits: scale * sum_k img * (softmax(sa)*K) -----------
__global__ __launch_bounds__(256) void cls_kernel(const float* __restrict__ img,
                                                  const float* __restrict__ sa,
                                                  const float* __restrict__ scale,
                                                  float* __restrict__ out_cls) {
  int gid = blockIdx.x * 256 + threadIdx.x;
  if (gid >= 64 * 200) return;
  int b = gid / 200, c = gid - b * 200;
  float s5[KKp];
  float mx = -1e30f;
#pragma unroll
  for (int k = 0; k < KKp; ++k) { s5[k] = sa[c * KKp + k]; mx = fmaxf(mx, s5[k]); }
  float den = 0.0f;
#pragma unroll
  for (int k = 0; k < KKp; ++k) { s5[k] = expf(s5[k] - mx); den += s5[k]; }
  float acc = 0.0f;
#pragma unroll
  for (int k = 0; k < KKp; ++k)
    acc += img[(size_t)b * CKD + c * KKp + k] * (s5[k] / den * 5.0f);
  out_cls[gid] = scale[0] * acc;
}

// ---------------- pseudo labels + softmax init of Q + class counts ------------
__global__ __launch_bounds__(256) void pseudo_kernel(const void* __restrict__ masks,
                                                     const int* __restrict__ labels,
                                                     const float* __restrict__ L,
                                                     const int* __restrict__ flag,
                                                     int* __restrict__ pl,
                                                     float* __restrict__ out_pseudo,
                                                     float* __restrict__ Q,
                                                     int* __restrict__ counts) {
  int n = blockIdx.x * 256 + threadIdx.x;
  if (n >= NTOK) return;
  int f = *flag;
  int m;
  if (f & 1)      m = ((const float*)masks)[n] != 0.0f;          // float32 bools
  else if (f & 2) m = ((const unsigned char*)masks)[n] != 0;     // byte-packed bools
  else            m = ((const int*)masks)[n] != 0;               // int32 bools
  int lab = m ? labels[n >> 8] : BGC;
  pl[n] = lab;
  out_pseudo[n] = (float)lab;
  atomicAdd(&counts[lab], 1);
  const float* Lr = L + (size_t)n * CKD + lab * KKp;
  float q[KKp];
  float mx = -1e30f;
#pragma unroll
  for (int k = 0; k < KKp; ++k) { q[k] = Lr[k]; mx = fmaxf(mx, q[k]); }
  float den = 0.0f;
#pragma unroll
  for (int k = 0; k < KKp; ++k) { q[k] = expf(q[k] - mx); den += q[k]; }
  float inv = 1.0f / den;
#pragma unroll
  for (int k = 0; k < KKp; ++k) Q[(size_t)n * KKp + k] = q[k] * inv;
}

// ---------------- prefix sum of counts (tiny) ---------------------------------
__global__ void prefix_kernel(const int* __restrict__ counts, int* __restrict__ offsets,
                              int* __restrict__ cursors) {
  if (threadIdx.x == 0 && blockIdx.x == 0) {
    int acc = 0;
    for (int c = 0; c < CC; ++c) { offsets[c] = acc; cursors[c] = acc; acc += counts[c]; }
    offsets[CC] = acc;
  }
}

// ---------------- scatter patches into class-sorted order --------------------
__global__ __launch_bounds__(256) void scatter_kernel(const int* __restrict__ pl,
                                                      int* __restrict__ cursors,
                                                      int* __restrict__ order) {
  int n = blockIdx.x * 256 + threadIdx.x;
  if (n >= NTOK) return;
  int pos = atomicAdd(&cursors[pl[n]], 1);
  order[pos] = n;
}

// ---------------- Sinkhorn column sums (deterministic, block per class) -------
__global__ __launch_bounds__(256) void colsum_kernel(const float* __restrict__ Q,
                                                     const int* __restrict__ pl,
                                                     float* __restrict__ colsum) {
  int c = blockIdx.x;
  float s[KKp] = {0, 0, 0, 0, 0};
  for (int n = threadIdx.x; n < NTOK; n += 256) {
    if (pl[n] == c) {
#pragma unroll
      for (int k = 0; k < KKp; ++k) s[k] += Q[(size_t)n * KKp + k];
    }
  }
#pragma unroll
  for (int off = 32; off; off >>= 1)
#pragma unroll
    for (int k = 0; k < KKp; ++k) s[k] += __shfl_xor(s[k], off, 64);
  __shared__ float wsum[4][KKp];
  int lane = threadIdx.x & 63, w = threadIdx.x >> 6;
  if (lane == 0) {
#pragma unroll
    for (int k = 0; k < KKp; ++k) wsum[w][k] = s[k];
  }
  __syncthreads();
  if (threadIdx.x == 0) {
#pragma unroll
    for (int k = 0; k < KKp; ++k)
      colsum[c * KKp + k] = wsum[0][k] + wsum[1][k] + wsum[2][k] + wsum[3][k];
  }
}

// ---------------- Sinkhorn row update ----------------------------------------
__global__ __launch_bounds__(256) void rowupd_kernel(float* __restrict__ Q,
                                                     const int* __restrict__ pl,
                                                     const float* __restrict__ colsum) {
  int n = blockIdx.x * 256 + threadIdx.x;
  if (n >= NTOK) return;
  int c = pl[n];
  float q[KKp];
  float r = 0.0f;
#pragma unroll
  for (int k = 0; k < KKp; ++k) {
    q[k] = Q[(size_t)n * KKp + k] / (colsum[c * KKp + k] + 1e-12f);
    r += q[k];
  }
  float rinv = 1.0f / (r + 1e-12f);
#pragma unroll
  for (int k = 0; k < KKp; ++k) Q[(size_t)n * KKp + k] = q[k] * rinv;
}

// ---------------- P_new accumulation (class-sorted chunks) --------------------
__global__ __launch_bounds__(256) void pnew_kernel(const int* __restrict__ offsets,
                                                   const int* __restrict__ order,
                                                   const float* __restrict__ Q,
                                                   const float* __restrict__ tok,
                                                   const float* __restrict__ inv_tok,
                                                   float* __restrict__ P_acc) {
  int c = blockIdx.x;
  int start = offsets[c], end = offsets[c + 1];
  int cstart = start + blockIdx.y * 256;
  if (cstart >= end) return;
  int cend = min(end, cstart + 256);
  int t = threadIdx.x;
  float acc[KKp][3];
#pragma unroll
  for (int k = 0; k < KKp; ++k)
#pragma unroll
    for (int s = 0; s < 3; ++s) acc[k][s] = 0.0f;

  for (int p = cstart; p < cend; ++p) {
    int n = order[p];
    float it = inv_tok[n];
    float q[KKp];
#pragma unroll
    for (int k = 0; k < KKp; ++k) q[k] = Q[(size_t)n * KKp + k];
#pragma unroll
    for (int s = 0; s < 3; ++s) {
      float v = tok[(size_t)n * DIMD + s * 256 + t] * it;
#pragma unroll
      for (int k = 0; k < KKp; ++k) acc[k][s] = fmaf(q[k], v, acc[k][s]);
    }
  }
#pragma unroll
  for (int k = 0; k < KKp; ++k)
#pragma unroll
    for (int s = 0; s < 3; ++s)
      atomicAdd(&P_acc[((size_t)c * KKp + k) * DIMD + s * 256 + t], acc[k][s]);
}

// ---------------- prototype EMA ------------------------------------------------
__global__ __launch_bounds__(256) void newproto_kernel(const float* __restrict__ proto,
                                                       const float* __restrict__ P_acc,
                                                       const int* __restrict__ counts,
                                                       float* __restrict__ outp) {
  int gid = blockIdx.x * 256 + threadIdx.x;
  if (gid >= CC * KKp * DIMD) return;
  int c = gid / (KKp * DIMD);
  float p = proto[gid];
  outp[gid] = (counts[c] > 0) ? (0.999f * p + 0.001f * P_acc[gid]) : p;
}

// ---------------- part assignment argmax ---------------------------------------
__global__ __launch_bounds__(256) void argmax_kernel(const float* __restrict__ Q,
                                                     float* __restrict__ out_part) {
  int n = blockIdx.x * 256 + threadIdx.x;
  if (n >= NTOK) return;
  float best = Q[(size_t)n * KKp];
  int bi = 0;
#pragma unroll
  for (int k = 1; k < KKp; ++k) {
    float v = Q[(size_t)n * KKp + k];
    if (v > best) { best = v; bi = k; }   // strict > keeps first max (jnp.argmax)
  }
  out_part[n] = (float)bi;
}

extern "C" void kernel_launch(void* const* d_in, const int* in_sizes, int n_in,
                              void* d_out, int out_size, void* d_ws, size_t ws_size,
                              hipStream_t stream) {
  const float* patch_tokens = (const float*)d_in[0];
  const float* prototypes   = (const float*)d_in[1];
  const float* sa           = (const float*)d_in[2];
  const float* scale        = (const float*)d_in[3];
  const int*   labels       = (const int*)d_in[4];
  const void*  masks        = (const void*)d_in[5];

  float* out = (float*)d_out;
  float* out_logits  = out + OUT_LOGITS;
  float* out_img     = out + OUT_IMG;
  float* out_cls     = out + OUT_CLS;
  float* out_part    = out + OUT_PART;
  float* out_newp    = out + OUT_NEWPROTO;
  float* out_pseudo  = out + OUT_PSEUDO;

  char* w = (char*)d_ws;
  float* P_acc   = (float*)(w + WOFF_PACC);
  int*   counts  = (int*)(w + WOFF_COUNTS);
  int*   flag    = (int*)(w + WOFF_FLAG);
  float* inv_tok = (float*)(w + WOFF_INVTOK);
  float* inv_pro = (float*)(w + WOFF_INVPRO);
  int*   pl      = (int*)(w + WOFF_PL);
  float* Q       = (float*)(w + WOFF_Q);
  float* colsum  = (float*)(w + WOFF_COLSUM);
  int*   offsets = (int*)(w + WOFF_OFFSETS);
  int*   cursors = (int*)(w + WOFF_CURSORS);
  int*   order   = (int*)(w + WOFF_ORDER);

  hipMemsetAsync(d_ws, 0, WS_ZERO_B, stream);

  norms_kernel<<<(NTOK + NPRO + 3) / 4, 256, 0, stream>>>(patch_tokens, prototypes,
                                                          inv_tok, inv_pro);
  maskprobe_kernel<<<16, 256, 0, stream>>>((const unsigned*)masks, flag);

  gemm_kernel<<<dim3(128, 8), 256, 0, stream>>>(patch_tokens, prototypes,
                                                inv_tok, inv_pro, out_logits);

  mean_kernel<<<252, 256, 0, stream>>>(out_logits, out_img);
  cls_kernel<<<50, 256, 0, stream>>>(out_img, sa, scale, out_cls);

  pseudo_kernel<<<64, 256, 0, stream>>>(masks, labels, out_logits, flag,
                                        pl, out_pseudo, Q, counts);
  prefix_kernel<<<1, 64, 0, stream>>>(counts, offsets, cursors);
  scatter_kernel<<<64, 256, 0, stream>>>(pl, cursors, order);

  for (int it = 0; it < 3; ++it) {
    colsum_kernel<<<CC, 256, 0, stream>>>(Q, pl, colsum);
    rowupd_kernel<<<64, 256, 0, stream>>>(Q, pl, colsum);
  }

  pnew_kernel<<<dim3(CC, 64), 256, 0, stream>>>(offsets, order, Q,
                                                patch_tokens, inv_tok, P_acc);
  newproto_kernel<<<3015, 256, 0, stream>>>(prototypes, P_acc, counts, out_newp);
  argmax_kernel<<<64, 256, 0, stream>>>(Q, out_part);
}

// Round 3
// 335.043 us; speedup vs baseline: 2.4861x; 2.4861x over previous
//
#include <hip/hip_runtime.h>
#include <math.h>

// Problem constants
#define NTOK 16384     // B*N_PATCH
#define NPRO 1005      // C*K
#define DIMD 768
#define CKD  1005
#define CC   201
#define KKp  5
#define BGC  200
#define KEXP 2304      // expanded K = 3*768 (hh, lh, hl)
#define KA   1536      // A2 row length ([Ah|Al])
#define NPAD 1024      // padded N

// d_out section offsets (floats)
#define OUT_LOGITS   0
#define OUT_IMG      16465920
#define OUT_CLS      (OUT_IMG + 64320)
#define OUT_PART     (OUT_CLS + 12800)
#define OUT_NEWPROTO (OUT_PART + 16384)
#define OUT_PSEUDO   (OUT_NEWPROTO + 771840)

// ws byte offsets
#define WOFF_PACC    0
#define WOFF_COUNTS  3087360
#define WOFF_FLAG    3088384
#define WS_ZERO_B    3088640
#define WOFF_A2      3088640ULL            // 16384*1536*2 = 50,331,648
#define WOFF_B2      53420288ULL           // 1024*2304*2  =  4,718,592
#define WOFF_INVTOK  58138880ULL
#define WOFF_PL      58204416ULL
#define WOFF_Q       58269952ULL
#define WOFF_COLSUM  58597632ULL
#define WOFF_OFFSETS 58601728ULL
#define WOFF_CURSORS 58602752ULL
#define WOFF_ORDER   58603776ULL

typedef __attribute__((ext_vector_type(8))) short short8;
typedef __attribute__((ext_vector_type(4))) float f32x4;
typedef __attribute__((ext_vector_type(4))) unsigned short usv4;

__device__ __forceinline__ unsigned short f2bf(float x) {
  unsigned int b = __float_as_uint(x);
  unsigned int r = (b + 0x7FFFu + ((b >> 16) & 1u)) >> 16;
  return (unsigned short)r;
}
__device__ __forceinline__ float bf2f(unsigned short u) {
  return __uint_as_float(((unsigned int)u) << 16);
}

__device__ __forceinline__ void async_copy16(const void* g, void* lds) {
  __builtin_amdgcn_global_load_lds(
      (const __attribute__((address_space(1))) unsigned int*)g,
      (__attribute__((address_space(3))) unsigned int*)lds, 16, 0, 0);
}

// ---------------- convert tokens: normalize + hi/lo bf16 split -> A2 --------
// A2[row][0:768] = bf16(x), A2[row][768:1536] = bf16(x - hi). Also inv_tok.
__global__ __launch_bounds__(256) void conv_tok_kernel(const float* __restrict__ tok,
                                                       unsigned short* __restrict__ A2,
                                                       float* __restrict__ inv_tok) {
  int wid = (blockIdx.x * 256 + threadIdx.x) >> 6;
  int lane = threadIdx.x & 63;
  if (wid >= NTOK) return;
  const float4* s4 = (const float4*)(tok + (size_t)wid * DIMD);
  float4 v[3];
  float s = 0.0f;
#pragma unroll
  for (int p = 0; p < 3; ++p) {
    v[p] = s4[p * 64 + lane];
    s += v[p].x * v[p].x + v[p].y * v[p].y + v[p].z * v[p].z + v[p].w * v[p].w;
  }
#pragma unroll
  for (int off = 32; off; off >>= 1) s += __shfl_xor(s, off, 64);
  float inv = 1.0f / (sqrtf(s) + 1e-12f);
  if (lane == 0) inv_tok[wid] = inv;
  unsigned short* rowp = A2 + (size_t)wid * KA;
#pragma unroll
  for (int p = 0; p < 3; ++p) {
    float x0 = v[p].x * inv, x1 = v[p].y * inv, x2 = v[p].z * inv, x3 = v[p].w * inv;
    usv4 hi, lo;
    hi.x = f2bf(x0); hi.y = f2bf(x1); hi.z = f2bf(x2); hi.w = f2bf(x3);
    lo.x = f2bf(x0 - bf2f(hi.x)); lo.y = f2bf(x1 - bf2f(hi.y));
    lo.z = f2bf(x2 - bf2f(hi.z)); lo.w = f2bf(x3 - bf2f(hi.w));
    int c = p * 256 + lane * 4;
    *(usv4*)(rowp + c) = hi;
    *(usv4*)(rowp + 768 + c) = lo;
  }
}

// ---------------- convert prototypes -> B2 = [Bh | Bh | Bl], padded to 1024 --
__global__ __launch_bounds__(256) void conv_pro_kernel(const float* __restrict__ pro,
                                                       unsigned short* __restrict__ B2) {
  int wid = (blockIdx.x * 256 + threadIdx.x) >> 6;
  int lane = threadIdx.x & 63;
  if (wid >= NPAD) return;
  unsigned short* rowp = B2 + (size_t)wid * KEXP;
  if (wid >= NPRO) {
    usv4 z = {0, 0, 0, 0};
#pragma unroll
    for (int p = 0; p < 3; ++p) {
      int c = p * 256 + lane * 4;
      *(usv4*)(rowp + c) = z; *(usv4*)(rowp + 768 + c) = z; *(usv4*)(rowp + 1536 + c) = z;
    }
    return;
  }
  const float4* s4 = (const float4*)(pro + (size_t)wid * DIMD);
  float4 v[3];
  float s = 0.0f;
#pragma unroll
  for (int p = 0; p < 3; ++p) {
    v[p] = s4[p * 64 + lane];
    s += v[p].x * v[p].x + v[p].y * v[p].y + v[p].z * v[p].z + v[p].w * v[p].w;
  }
#pragma unroll
  for (int off = 32; off; off >>= 1) s += __shfl_xor(s, off, 64);
  float inv = 1.0f / (sqrtf(s) + 1e-12f);
#pragma unroll
  for (int p = 0; p < 3; ++p) {
    float x0 = v[p].x * inv, x1 = v[p].y * inv, x2 = v[p].z * inv, x3 = v[p].w * inv;
    usv4 hi, lo;
    hi.x = f2bf(x0); hi.y = f2bf(x1); hi.z = f2bf(x2); hi.w = f2bf(x3);
    lo.x = f2bf(x0 - bf2f(hi.x)); lo.y = f2bf(x1 - bf2f(hi.y));
    lo.z = f2bf(x2 - bf2f(hi.z)); lo.w = f2bf(x3 - bf2f(hi.w));
    int c = p * 256 + lane * 4;
    *(usv4*)(rowp + c) = hi;
    *(usv4*)(rowp + 768 + c) = hi;
    *(usv4*)(rowp + 1536 + c) = lo;
  }
}

// ---------------- mask dtype probe (3-way) -----------------------------------
__global__ void maskprobe_kernel(const unsigned* __restrict__ masks, int* __restrict__ flag) {
  int i = blockIdx.x * 256 + threadIdx.x;
  if (i < 4096) {
    unsigned v = masks[i];
    if (v == 0x3F800000u)      atomicOr(flag, 1);
    else if (v > 1u)           atomicOr(flag, 2);
  }
}

// ---------------- MFMA GEMM: C[16384][1005] = A2 . B2^T over K'=2304 ---------
// 128x128 tile, BK=32, double-buffered LDS, global_load_lds(16B), m97 pattern.
// Epilogue: write logits + atomic column-means into img.
__global__ __launch_bounds__(256, 2) void gemm_kernel(const unsigned short* __restrict__ A2,
                                                      const unsigned short* __restrict__ B2,
                                                      float* __restrict__ C,
                                                      float* __restrict__ img) {
  __shared__ unsigned short As[2][4096];   // [128 rows][32 k] bf16
  __shared__ unsigned short Bs[2][4096];
  const int tid = threadIdx.x;
  const int lane = tid & 63, wave = tid >> 6;
  const int m0 = blockIdx.x * 128, n0 = blockIdx.y * 128;
  const int wr = wave >> 1, wc = wave & 1;

  f32x4 acc[4][4];
#pragma unroll
  for (int i = 0; i < 4; ++i)
#pragma unroll
    for (int j = 0; j < 4; ++j) acc[i][j] = (f32x4){0.f, 0.f, 0.f, 0.f};

  const int r4 = lane >> 2;          // 0..15 row-in-segment
  const int kc = (lane & 3) * 8;     // element offset in BK

  // stage K-step kt into buffer buf
  auto STAGE = [&](int buf, int kt) {
    int kb = kt * 32;
    int acol = (kb < KA ? kb : kb - KA) + kc;
    int bcol = kb + kc;
#pragma unroll
    for (int j = 0; j < 2; ++j) {
      int seg = wave * 2 + j;
      async_copy16(A2 + (size_t)(m0 + seg * 16 + r4) * KA + acol, &As[buf][seg * 512]);
      async_copy16(B2 + (size_t)(n0 + seg * 16 + r4) * KEXP + bcol, &Bs[buf][seg * 512]);
    }
  };

  STAGE(0, 0);
  __syncthreads();

  const int rb = wr * 64 + (lane & 15);
  const int cb = wc * 64 + (lane & 15);
  const int hi8 = (lane >> 4) * 8;

  int cur = 0;
  for (int kt = 0; kt < 72; ++kt) {
    if (kt < 71) STAGE(cur ^ 1, kt + 1);
    short8 a[4], b[4];
#pragma unroll
    for (int f = 0; f < 4; ++f) {
      a[f] = *(const short8*)&As[cur][(rb + f * 16) * 32 + hi8];
      b[f] = *(const short8*)&Bs[cur][(cb + f * 16) * 32 + hi8];
    }
#pragma unroll
    for (int fm = 0; fm < 4; ++fm)
#pragma unroll
      for (int fn = 0; fn < 4; ++fn)
        acc[fm][fn] = __builtin_amdgcn_mfma_f32_16x16x32_bf16(a[fm], b[fn], acc[fm][fn], 0, 0, 0);
    __syncthreads();
    cur ^= 1;
  }

  // epilogue: C writes + fused mean-pool (rows of this block are one image)
  const int bimg = m0 >> 8;
#pragma unroll
  for (int fn = 0; fn < 4; ++fn) {
    int col = n0 + wc * 64 + fn * 16 + (lane & 15);
    float s = 0.0f;
#pragma unroll
    for (int fm = 0; fm < 4; ++fm) {
      int row = m0 + wr * 64 + fm * 16 + (lane >> 4) * 4;
      f32x4 v = acc[fm][fn];
      if (col < NPRO) {
        C[(size_t)(row + 0) * CKD + col] = v.x;
        C[(size_t)(row + 1) * CKD + col] = v.y;
        C[(size_t)(row + 2) * CKD + col] = v.z;
        C[(size_t)(row + 3) * CKD + col] = v.w;
      }
      s += v.x + v.y + v.z + v.w;
    }
    s += __shfl_xor(s, 16, 64);
    s += __shfl_xor(s, 32, 64);
    if (lane < 16 && col < NPRO)
      atomicAdd(&img[bimg * CKD + col], s * (1.0f / 256.0f));
  }
}

// ---------------- class logits -----------------------------------------------
__global__ __launch_bounds__(256) void cls_kernel(const float* __restrict__ img,
                                                  const float* __restrict__ sa,
                                                  const float* __restrict__ scale,
                                                  float* __restrict__ out_cls) {
  int gid = blockIdx.x * 256 + threadIdx.x;
  if (gid >= 64 * 200) return;
  int b = gid / 200, c = gid - b * 200;
  float s5[KKp];
  float mx = -1e30f;
#pragma unroll
  for (int k = 0; k < KKp; ++k) { s5[k] = sa[c * KKp + k]; mx = fmaxf(mx, s5[k]); }
  float den = 0.0f;
#pragma unroll
  for (int k = 0; k < KKp; ++k) { s5[k] = expf(s5[k] - mx); den += s5[k]; }
  float acc = 0.0f;
#pragma unroll
  for (int k = 0; k < KKp; ++k)
    acc += img[(size_t)b * CKD + c * KKp + k] * (s5[k] / den * 5.0f);
  out_cls[gid] = scale[0] * acc;
}

// ---------------- pseudo labels + Q softmax init + LDS-hist counts ------------
__global__ __launch_bounds__(256) void pseudo_kernel(const void* __restrict__ masks,
                                                     const int* __restrict__ labels,
                                                     const float* __restrict__ L,
                                                     const int* __restrict__ flag,
                                                     int* __restrict__ pl,
                                                     float* __restrict__ out_pseudo,
                                                     float* __restrict__ Q,
                                                     int* __restrict__ counts) {
  __shared__ int hist[CC];
  int t = threadIdx.x;
  if (t < CC) hist[t] = 0;
  __syncthreads();
  int n = blockIdx.x * 256 + t;
  int f = *flag;
  int m;
  if (f & 1)      m = ((const float*)masks)[n] != 0.0f;
  else if (f & 2) m = ((const unsigned char*)masks)[n] != 0;
  else            m = ((const int*)masks)[n] != 0;
  int lab = m ? labels[n >> 8] : BGC;
  pl[n] = lab;
  out_pseudo[n] = (float)lab;
  atomicAdd(&hist[lab], 1);
  const float* Lr = L + (size_t)n * CKD + lab * KKp;
  float q[KKp];
  float mx = -1e30f;
#pragma unroll
  for (int k = 0; k < KKp; ++k) { q[k] = Lr[k]; mx = fmaxf(mx, q[k]); }
  float den = 0.0f;
#pragma unroll
  for (int k = 0; k < KKp; ++k) { q[k] = expf(q[k] - mx); den += q[k]; }
  float inv = 1.0f / den;
#pragma unroll
  for (int k = 0; k < KKp; ++k) Q[(size_t)n * KKp + k] = q[k] * inv;
  __syncthreads();
  if (t < CC && hist[t] > 0) atomicAdd(&counts[t], hist[t]);
}

// ---------------- parallel exclusive scan of counts ---------------------------
__global__ void prefix_kernel(const int* __restrict__ counts, int* __restrict__ offsets,
                              int* __restrict__ cursors) {
  __shared__ int sc[256];
  int t = threadIdx.x;
  int v = (t < CC) ? counts[t] : 0;
  sc[t] = v;
  __syncthreads();
  for (int off = 1; off < 256; off <<= 1) {
    int u = (t >= off) ? sc[t - off] : 0;
    __syncthreads();
    sc[t] += u;
    __syncthreads();
  }
  if (t < CC) { int excl = sc[t] - v; offsets[t] = excl; cursors[t] = excl; }
  if (t == CC - 1) offsets[CC] = sc[t];
}

// ---------------- block-ranked scatter into class-sorted order ----------------
__global__ __launch_bounds__(256) void scatter_kernel(const int* __restrict__ pl,
                                                      int* __restrict__ cursors,
                                                      int* __restrict__ order) {
  __shared__ int hist[CC], base[CC];
  int t = threadIdx.x;
  for (int c = t; c < CC; c += 256) hist[c] = 0;
  __syncthreads();
  int n = blockIdx.x * 256 + t;
  int c = pl[n];
  int rank = atomicAdd(&hist[c], 1);
  __syncthreads();
  for (int cc = t; cc < CC; cc += 256)
    if (hist[cc] > 0) base[cc] = atomicAdd(&cursors[cc], hist[cc]);
  __syncthreads();
  order[base[c] + rank] = n;
}

// ---------------- Sinkhorn column sums over sorted range ----------------------
__global__ __launch_bounds__(256) void colsum_kernel(const float* __restrict__ Q,
                                                     const int* __restrict__ order,
                                                     const int* __restrict__ offsets,
                                                     float* __restrict__ colsum) {
  int c = blockIdx.x;
  int s0 = offsets[c], e0 = offsets[c + 1];
  float a[KKp] = {0, 0, 0, 0, 0};
  for (int i = s0 + threadIdx.x; i < e0; i += 256) {
    int n = order[i];
    const float* q = Q + (size_t)n * KKp;
#pragma unroll
    for (int k = 0; k < KKp; ++k) a[k] += q[k];
  }
#pragma unroll
  for (int off = 32; off; off >>= 1)
#pragma unroll
    for (int k = 0; k < KKp; ++k) a[k] += __shfl_xor(a[k], off, 64);
  __shared__ float wsum[4][KKp];
  int lane = threadIdx.x & 63, w = threadIdx.x >> 6;
  if (lane == 0) {
#pragma unroll
    for (int k = 0; k < KKp; ++k) wsum[w][k] = a[k];
  }
  __syncthreads();
  if (threadIdx.x == 0) {
#pragma unroll
    for (int k = 0; k < KKp; ++k)
      colsum[c * KKp + k] = wsum[0][k] + wsum[1][k] + wsum[2][k] + wsum[3][k];
  }
}

// ---------------- Sinkhorn row update ----------------------------------------
__global__ __launch_bounds__(256) void rowupd_kernel(float* __restrict__ Q,
                                                     const int* __restrict__ pl,
                                                     const float* __restrict__ colsum) {
  int n = blockIdx.x * 256 + threadIdx.x;
  if (n >= NTOK) return;
  int c = pl[n];
  float q[KKp];
  float r = 0.0f;
#pragma unroll
  for (int k = 0; k < KKp; ++k) {
    q[k] = Q[(size_t)n * KKp + k] / (colsum[c * KKp + k] + 1e-12f);
    r += q[k];
  }
  float rinv = 1.0f / (r + 1e-12f);
#pragma unroll
  for (int k = 0; k < KKp; ++k) Q[(size_t)n * KKp + k] = q[k] * rinv;
}

// ---------------- P_new accumulation: 32-patch chunks, flush on class change --
__global__ __launch_bounds__(256) void pnew_kernel(const int* __restrict__ order,
                                                   const int* __restrict__ pl,
                                                   const float* __restrict__ Q,
                                                   const float* __restrict__ tok,
                                                   const float* __restrict__ inv_tok,
                                                   float* __restrict__ P_acc) {
  __shared__ int idx[32], cls[32];
  int t = threadIdx.x;
  int p0 = blockIdx.x * 32;
  if (t < 32) {
    int n = order[p0 + t];
    idx[t] = n;
    cls[t] = pl[n];
  }
  __syncthreads();
  float acc[KKp][3];
#pragma unroll
  for (int k = 0; k < KKp; ++k)
#pragma unroll
    for (int s = 0; s < 3; ++s) acc[k][s] = 0.0f;
  int cur = cls[0];
  for (int i = 0; i < 32; ++i) {
    int c = cls[i];
    if (c != cur) {
#pragma unroll
      for (int k = 0; k < KKp; ++k)
#pragma unroll
        for (int s = 0; s < 3; ++s) {
          atomicAdd(&P_acc[((size_t)cur * KKp + k) * DIMD + s * 256 + t], acc[k][s]);
          acc[k][s] = 0.0f;
        }
      cur = c;
    }
    int n = idx[i];
    float it = inv_tok[n];
    float q[KKp];
#pragma unroll
    for (int k = 0; k < KKp; ++k) q[k] = Q[(size_t)n * KKp + k];
#pragma unroll
    for (int s = 0; s < 3; ++s) {
      float v = tok[(size_t)n * DIMD + s * 256 + t] * it;
#pragma unroll
      for (int k = 0; k < KKp; ++k) acc[k][s] = fmaf(q[k], v, acc[k][s]);
    }
  }
#pragma unroll
  for (int k = 0; k < KKp; ++k)
#pragma unroll
    for (int s = 0; s < 3; ++s)
      atomicAdd(&P_acc[((size_t)cur * KKp + k) * DIMD + s * 256 + t], acc[k][s]);
}

// ---------------- prototype EMA ------------------------------------------------
__global__ __launch_bounds__(256) void newproto_kernel(const float* __restrict__ proto,
                                                       const float* __restrict__ P_acc,
                                                       const int* __restrict__ counts,
                                                       float* __restrict__ outp) {
  int gid = blockIdx.x * 256 + threadIdx.x;
  if (gid >= CC * KKp * DIMD) return;
  int c = gid / (KKp * DIMD);
  float p = proto[gid];
  outp[gid] = (counts[c] > 0) ? (0.999f * p + 0.001f * P_acc[gid]) : p;
}

// ---------------- part assignment argmax ---------------------------------------
__global__ __launch_bounds__(256) void argmax_kernel(const float* __restrict__ Q,
                                                     float* __restrict__ out_part) {
  int n = blockIdx.x * 256 + threadIdx.x;
  if (n >= NTOK) return;
  float best = Q[(size_t)n * KKp];
  int bi = 0;
#pragma unroll
  for (int k = 1; k < KKp; ++k) {
    float v = Q[(size_t)n * KKp + k];
    if (v > best) { best = v; bi = k; }
  }
  out_part[n] = (float)bi;
}

extern "C" void kernel_launch(void* const* d_in, const int* in_sizes, int n_in,
                              void* d_out, int out_size, void* d_ws, size_t ws_size,
                              hipStream_t stream) {
  const float* patch_tokens = (const float*)d_in[0];
  const float* prototypes   = (const float*)d_in[1];
  const float* sa           = (const float*)d_in[2];
  const float* scale        = (const float*)d_in[3];
  const int*   labels       = (const int*)d_in[4];
  const void*  masks        = (const void*)d_in[5];

  float* out = (float*)d_out;
  float* out_logits  = out + OUT_LOGITS;
  float* out_img     = out + OUT_IMG;
  float* out_cls     = out + OUT_CLS;
  float* out_part    = out + OUT_PART;
  float* out_newp    = out + OUT_NEWPROTO;
  float* out_pseudo  = out + OUT_PSEUDO;

  char* w = (char*)d_ws;
  float*          P_acc   = (float*)(w + WOFF_PACC);
  int*            counts  = (int*)(w + WOFF_COUNTS);
  int*            flag    = (int*)(w + WOFF_FLAG);
  unsigned short* A2      = (unsigned short*)(w + WOFF_A2);
  unsigned short* B2      = (unsigned short*)(w + WOFF_B2);
  float*          inv_tok = (float*)(w + WOFF_INVTOK);
  int*            pl      = (int*)(w + WOFF_PL);
  float*          Q       = (float*)(w + WOFF_Q);
  float*          colsum  = (float*)(w + WOFF_COLSUM);
  int*            offsets = (int*)(w + WOFF_OFFSETS);
  int*            cursors = (int*)(w + WOFF_CURSORS);
  int*            order   = (int*)(w + WOFF_ORDER);

  hipMemsetAsync(d_ws, 0, WS_ZERO_B, stream);
  hipMemsetAsync(out_img, 0, (size_t)64 * CKD * sizeof(float), stream);

  maskprobe_kernel<<<16, 256, 0, stream>>>((const unsigned*)masks, flag);
  conv_tok_kernel<<<4096, 256, 0, stream>>>(patch_tokens, A2, inv_tok);
  conv_pro_kernel<<<256, 256, 0, stream>>>(prototypes, B2);

  gemm_kernel<<<dim3(128, 8), 256, 0, stream>>>(A2, B2, out_logits, out_img);

  cls_kernel<<<50, 256, 0, stream>>>(out_img, sa, scale, out_cls);

  pseudo_kernel<<<64, 256, 0, stream>>>(masks, labels, out_logits, flag,
                                        pl, out_pseudo, Q, counts);
  prefix_kernel<<<1, 256, 0, stream>>>(counts, offsets, cursors);
  scatter_kernel<<<64, 256, 0, stream>>>(pl, cursors, order);

  for (int it = 0; it < 3; ++it) {
    colsum_kernel<<<CC, 256, 0, stream>>>(Q, order, offsets, colsum);
    rowupd_kernel<<<64, 256, 0, stream>>>(Q, pl, colsum);
  }

  pnew_kernel<<<512, 256, 0, stream>>>(order, pl, Q, patch_tokens, inv_tok, P_acc);
  newproto_kernel<<<3015, 256, 0, stream>>>(prototypes, P_acc, counts, out_newp);
  argmax_kernel<<<64, 256, 0, stream>>>(Q, out_part);
}